// Round 8
// baseline (116.765 us; speedup 1.0000x reference)
//
#include <hip/hip_runtime.h>

#define HH 64
#define WW 64
#define NN 4096
#define DZc 128
#define KS 8
#define KRANGE (NN / KS)          // 512 n per block
#define NSTEP (KRANGE / 16)       // 32 ksteps of K=16, barrier-free
#define CELLS 2097152             // 4*64*64*128 output floats
#define WS_NEED (8ull * CELLS * 2ull)   // f16 partials: 32 MB

typedef __fp16 v2fp16 __attribute__((ext_vector_type(2)));
typedef _Float16 v4h __attribute__((ext_vector_type(4)));
typedef _Float16 v8h __attribute__((ext_vector_type(8)));
typedef float v16f __attribute__((ext_vector_type(16)));

__device__ __forceinline__ unsigned pk16(float lo, float hi){
  union { v2fp16 h; unsigned u; } c;
  c.h = __builtin_amdgcn_cvt_pkrtz(lo, hi);
  return c.u;
}
__device__ __forceinline__ float fexp2(float x){ return __builtin_amdgcn_exp2f(x); }

__global__ void init_out_kernel(const float4* __restrict__ zc_on,
                                const int* __restrict__ ignore,
                                float4* __restrict__ out){
  int i = blockIdx.x * blockDim.x + threadIdx.x;
  float4 v = zc_on[i];
  if (ignore[0]) { v.x = 0.f; v.y = 0.f; v.z = 0.f; v.w = 0.f; }
  out[i] = v;
}

// sum 8 f16 K-split partials + zc_on -> out
__global__ void reduce_kernel(const v4h* __restrict__ part,
                              const float4* __restrict__ zc_on,
                              const int* __restrict__ ignore,
                              float4* __restrict__ out){
  int i = blockIdx.x * blockDim.x + threadIdx.x;
  float4 s = zc_on[i];
  if (ignore[0]) { s.x = 0.f; s.y = 0.f; s.z = 0.f; s.w = 0.f; }
  #pragma unroll
  for (int ks = 0; ks < KS; ++ks){
    v4h p = part[(size_t)ks * (CELLS / 4) + i];
    s.x += (float)p[0]; s.y += (float)p[1]; s.z += (float)p[2]; s.w += (float)p[3];
  }
  out[i] = s;
}

// BARRIER-FREE k-loop (r7 post-mortem: per-ktile __syncthreads + staging chain
// was the bound, not occupancy/pipes).
// Grid: 1024 blocks = ks(8, HIGH) x b(4) x mt(32); 4 blocks/CU, 16 indep waves.
// Block: BM=128 (16iy x 8ix) x BD=128; wave = 64m x 64d (wm x wdh).
// Prologue: whole-K g-table (24 rows x 512 k, f16, 25KB LDS) -> ONE barrier.
// Loop: 32 ksteps; B-frags DIRECT from global (16 coalesced dword loads,
// rolling 1-kstep prefetch), cvt_pkrtz -> f16; A-frags = gy*gx from gtab
// (3x ds_read_b128, <=2-way); 4 MFMA 32x32x16. No __syncthreads anywhere.
__global__ __launch_bounds__(256, 4)
void setconv_gemm_kernel(const float* __restrict__ xc_off,
                         const float* __restrict__ xc_on,
                         const float* __restrict__ zc_off,
                         const float* __restrict__ lsp,
                         _Float16* __restrict__ part,
                         float* __restrict__ out)
{
  __shared__ unsigned short gt[24 * 520];   // rows 0-15 gy, 16-23 gx; stride 520 halves

  const int tid = threadIdx.x;
  const int bid = blockIdx.x;
  const int ks  = bid >> 7;          // HIGH bits -> same-XCD partial groups
  const int rem = bid & 127;
  const int b   = rem >> 5;
  const int mt  = rem & 31;
  const int iy0 = (mt >> 3) * 16;
  const int ix0 = (mt & 7) * 8;
  const int nbase = ks * KRANGE;

  const float lsy = 1e-5f + log1pf(expf(lsp[0]));
  const float lsx = 1e-5f + log1pf(expf(lsp[1]));
  const float LOG2E = 1.44269504088896340736f;
  const float ay = -0.5f * LOG2E / (lsy * lsy);
  const float ax = -0.5f * LOG2E / (lsx * lsx);

  const float* xb = xc_off + (size_t)b * NN * 2;
  const float* zb = zc_off + (size_t)b * NN * DZc;

  // ---- prologue: whole-K g-table, one barrier.
  // thread -> rows 3g..3g+2 (g=tid>>5), k-pairs p = (tid&31) + 32j, j=0..7
  {
    const int g  = tid >> 5;
    const int p8 = tid & 31;
    float cc[3], aa[3];
    #pragma unroll
    for (int rr = 0; rr < 3; ++rr){
      int r = 3 * g + rr;
      if (r < 16){ cc[rr] = xc_on[((b * HH + iy0 + r) * WW) * 2];          aa[rr] = ay; }
      else       { cc[rr] = xc_on[(b * HH * WW + ix0 + (r - 16)) * 2 + 1]; aa[rr] = ax; }
    }
    unsigned* gtw = (unsigned*)gt;
    #pragma unroll
    for (int j = 0; j < 8; ++j){
      const int p = p8 + 32 * j;
      float4 xq = *(const float4*)&xb[(size_t)(nbase + 2 * p) * 2];  // y0,x0,y1,x1
      #pragma unroll
      for (int rr = 0; rr < 3; ++rr){
        int r = 3 * g + rr;
        float s0 = (r < 16) ? xq.x : xq.y;
        float s1 = (r < 16) ? xq.z : xq.w;
        float d0 = cc[rr] - s0, d1 = cc[rr] - s1;
        gtw[r * 260 + p] = pk16(fexp2(aa[rr] * d0 * d0), fexp2(aa[rr] * d1 * d1));
      }
    }
  }
  __syncthreads();   // the ONLY barrier

  // ---- consumer mapping
  const int lane = tid & 63;
  const int wv  = tid >> 6;
  const int wm  = wv >> 1;
  const int wdh = wv & 1;
  const int l31 = lane & 31;
  const int lh  = lane >> 5;
  const int gxr  = 16 + (l31 & 7);
  const int gyr0 = wm * 8 + (l31 >> 3);    // + mtl*4

  v16f acc[2][2];
  #pragma unroll
  for (int m = 0; m < 2; ++m)
    #pragma unroll
    for (int d = 0; d < 2; ++d)
      #pragma unroll
      for (int r = 0; r < 16; ++r)
        acc[m][d][r] = 0.f;

  // B-frag source: Z[nbase + s*16 + lh*8 + j][wdh*64 + dtl*32 + l31]
  const float* zp0 = zb + (size_t)(nbase + lh * 8) * DZc + wdh * 64 + l31;

  float pend[16];
  #pragma unroll
  for (int dtl = 0; dtl < 2; ++dtl)
    #pragma unroll
    for (int j = 0; j < 8; ++j)
      pend[dtl * 8 + j] = zp0[j * DZc + dtl * 32];

  #pragma unroll 1
  for (int s = 0; s < NSTEP; ++s){
    const int k0 = s * 16 + lh * 8;

    // cvt pending loads (issued last iteration) -> f16 B-frags
    v8h bfr[2];
    #pragma unroll
    for (int dtl = 0; dtl < 2; ++dtl){
      union { unsigned u[4]; v8h v; } u;
      #pragma unroll
      for (int jj = 0; jj < 4; ++jj)
        u.u[jj] = pk16(pend[dtl * 8 + 2 * jj], pend[dtl * 8 + 2 * jj + 1]);
      bfr[dtl] = u.v;
    }

    // issue next kstep's 16 loads (drain across this kstep's LDS+MFMA + 15 other waves)
    if (s + 1 < NSTEP){
      const float* zp = zp0 + (size_t)(s + 1) * 16 * DZc;
      #pragma unroll
      for (int dtl = 0; dtl < 2; ++dtl)
        #pragma unroll
        for (int j = 0; j < 8; ++j)
          pend[dtl * 8 + j] = zp[j * DZc + dtl * 32];
    }

    // A-frags from gtab (read-only; no sync needed) + 4 MFMA
    const v8h gx = *(const v8h*)&gt[gxr * 520 + k0];
    #pragma unroll
    for (int mtl = 0; mtl < 2; ++mtl){
      const v8h gy = *(const v8h*)&gt[(gyr0 + mtl * 4) * 520 + k0];
      v8h av = gy * gx;
      #pragma unroll
      for (int dtl = 0; dtl < 2; ++dtl)
        acc[mtl][dtl] = __builtin_amdgcn_mfma_f32_32x32x16_f16(av, bfr[dtl], acc[mtl][dtl], 0, 0, 0);
    }
  }

  // ---- epilogue
  // C/D of 32x32: col = lane&31 (d), row = (reg&3) + 8*(reg>>2) + 4*(lane>>5)
  if (part){
    _Float16* pw = part + (size_t)ks * CELLS;
    #pragma unroll
    for (int mtl = 0; mtl < 2; ++mtl)
      #pragma unroll
      for (int dtl = 0; dtl < 2; ++dtl){
        const int d = wdh * 64 + dtl * 32 + l31;
        #pragma unroll
        for (int reg = 0; reg < 16; ++reg){
          const int row = (reg & 3) + 8 * (reg >> 2) + 4 * lh;
          const int m = wm * 64 + mtl * 32 + row;
          const int iy = iy0 + (m >> 3);
          const int ix = ix0 + (m & 7);
          pw[((b * HH + iy) * WW + ix) * DZc + d] = (_Float16)acc[mtl][dtl][reg];
        }
      }
  } else {
    #pragma unroll
    for (int mtl = 0; mtl < 2; ++mtl)
      #pragma unroll
      for (int dtl = 0; dtl < 2; ++dtl){
        const int d = wdh * 64 + dtl * 32 + l31;
        #pragma unroll
        for (int reg = 0; reg < 16; ++reg){
          const int row = (reg & 3) + 8 * (reg >> 2) + 4 * lh;
          const int m = wm * 64 + mtl * 32 + row;
          const int iy = iy0 + (m >> 3);
          const int ix = ix0 + (m & 7);
          unsafeAtomicAdd(&out[((b * HH + iy) * WW + ix) * DZc + d], acc[mtl][dtl][reg]);
        }
      }
  }
}

extern "C" void kernel_launch(void* const* d_in, const int* in_sizes, int n_in,
                              void* d_out, int out_size, void* d_ws, size_t ws_size,
                              hipStream_t stream){
  const float* xc_off = (const float*)d_in[0];
  const float* xc_on  = (const float*)d_in[1];
  const float* zc_off = (const float*)d_in[2];
  const float* zc_on  = (const float*)d_in[3];
  const float* lsp    = (const float*)d_in[4];
  const int*   ign    = (const int*)d_in[5];
  float* out = (float*)d_out;

  if (ws_size >= WS_NEED){
    _Float16* part = (_Float16*)d_ws;
    setconv_gemm_kernel<<<KS * 128, 256, 0, stream>>>(xc_off, xc_on, zc_off, lsp, part, out);
    reduce_kernel<<<CELLS / 4 / 256, 256, 0, stream>>>((const v4h*)part, (const float4*)zc_on, ign, (float4*)out);
  } else {
    init_out_kernel<<<out_size / 1024, 256, 0, stream>>>((const float4*)zc_on, ign, (float4*)out);
    setconv_gemm_kernel<<<KS * 128, 256, 0, stream>>>(xc_off, xc_on, zc_off, lsp, nullptr, out);
  }
}